// Round 13
// baseline (25.887 us; speedup 1.0000x reference)
//
#include <hip/hip_runtime.h>
#include <math.h>
#include <string.h>

#define NJ 24
#define NV 6890
#define NB 128

// Ancestor chains (closest ancestor first), -1 padded. Max depth 8.
__constant__ int d_anc[NJ][8] = {
  {-1,-1,-1,-1,-1,-1,-1,-1},
  { 0,-1,-1,-1,-1,-1,-1,-1},
  { 0,-1,-1,-1,-1,-1,-1,-1},
  { 0,-1,-1,-1,-1,-1,-1,-1},
  { 1, 0,-1,-1,-1,-1,-1,-1},
  { 2, 0,-1,-1,-1,-1,-1,-1},
  { 3, 0,-1,-1,-1,-1,-1,-1},
  { 4, 1, 0,-1,-1,-1,-1,-1},
  { 5, 2, 0,-1,-1,-1,-1,-1},
  { 6, 3, 0,-1,-1,-1,-1,-1},
  { 7, 4, 1, 0,-1,-1,-1,-1},
  { 8, 5, 2, 0,-1,-1,-1,-1},
  { 9, 6, 3, 0,-1,-1,-1,-1},
  { 9, 6, 3, 0,-1,-1,-1,-1},
  { 9, 6, 3, 0,-1,-1,-1,-1},
  {12, 9, 6, 3, 0,-1,-1,-1},
  {13, 9, 6, 3, 0,-1,-1,-1},
  {14, 9, 6, 3, 0,-1,-1,-1},
  {16,13, 9, 6, 3, 0,-1,-1},
  {17,14, 9, 6, 3, 0,-1,-1},
  {18,16,13, 9, 6, 3, 0,-1},
  {19,17,14, 9, 6, 3, 0,-1},
  {20,18,16,13, 9, 6, 3, 0},
  {21,19,17,14, 9, 6, 3, 0}
};
__constant__ int d_par[NJ] = {-1,0,0,0,1,2,3,4,5,6,7,8,9,9,9,12,13,14,16,17,18,19,20,21};

typedef __attribute__((ext_vector_type(8))) short bf16x8;
typedef __attribute__((ext_vector_type(4))) float f32x4;

__device__ __forceinline__ short f2bf(float f) {
    unsigned int u;
    memcpy(&u, &f, 4);
    u += 0x7fffu + ((u >> 16) & 1u);   // round-to-nearest-even
    return (short)(u >> 16);
}

#define TLSTRIDE 20   // floats per scratch row: 80 B, 16B-aligned

// FUSED kernel, continuous-W-stream variant.
// Changes vs R12: (a) V prefetched into registers BEFORE the chain, so the
// epilogue has NO VMEM loads (in-order vmcnt waits there were draining the
// W stream once per 64-vert group); (b) 128 verts/wave (2 groups), and
// group-1's W loads are ISSUED after group-0's W->bf16 conversion but before
// group-0's MFMA/epilogue -- the W stream never goes idle within a wave.
// Grid doubled to (14, 128) for +waves/CU.
__global__ __launch_bounds__(256, 4) void lbs_fused(const float* __restrict__ V,
                                                    const float* __restrict__ J,
                                                    const float* __restrict__ pose,
                                                    const float* __restrict__ W,
                                                    float* __restrict__ out) {
    const int b    = blockIdx.y;
    const int tid  = threadIdx.x;
    const int wave = tid >> 6;
    const int lane = tid & 63;
    const int vwave = blockIdx.x * 512 + wave * 128;   // 128 verts per wave
    const int n16 = lane & 15;   // A: vertex slot | B: out-elem n | C: col
    const int g   = lane >> 4;   // k-group (8 joints per group)
    const bool wactive = (vwave < NV);

    __shared__ float A_lds[NJ][12];
    __shared__ float Gc_lds[NJ * 12];
    __shared__ float tl[4 * 64 * TLSTRIDE];

    // ---- Prefetch (in flight during the chain phase) ----
    // Group-0 W tiles.
    float4 pfl[4], pfh[4];
    #pragma unroll
    for (int t = 0; t < 4; t++) {
        pfl[t] = make_float4(0.f, 0.f, 0.f, 0.f);
        pfh[t] = make_float4(0.f, 0.f, 0.f, 0.f);
        if (wactive && g < 3) {
            const int v  = vwave + t * 16 + n16;
            const int vc = v < NV ? v : NV - 1;
            const float4* wp = (const float4*)(W + ((size_t)b * NV + vc) * 24 + g * 8);
            pfl[t] = wp[0];
            pfh[t] = wp[1];
        }
    }
    // V for this wave's two epilogue verts (registers; epilogue does no loads).
    float v0x = 0.f, v0y = 0.f, v0z = 0.f, v1x = 0.f, v1y = 0.f, v1z = 0.f;
    if (wactive) {
        const int e0 = vwave + lane;
        const int e0c = e0 < NV ? e0 : NV - 1;
        const float* vp0 = V + ((size_t)b * NV + e0c) * 3;
        v0x = vp0[0]; v0y = vp0[1]; v0z = vp0[2];
        const int e1 = vwave + 64 + lane;
        const int e1c = e1 < NV ? e1 : NV - 1;
        const float* vp1 = V + ((size_t)b * NV + e1c) * 3;
        v1x = vp1[0]; v1y = vp1[1]; v1z = vp1[2];
    }

    // ---- Phase 0: chain (all threads reach both barriers) ----
    if (tid < NJ) {
        const int i = tid;
        const float* p = pose + ((size_t)b * NJ + i) * 3;
        float rx = p[0], ry = p[1], rz = p[2];
        float ex = rx + 1e-8f, ey = ry + 1e-8f, ez = rz + 1e-8f;
        float theta = sqrtf(ex * ex + ey * ey + ez * ez);
        float inv = 1.0f / theta;
        float hx = rx * inv, hy = ry * inv, hz = rz * inv;
        float c = cosf(theta * (float)M_PI);
        float s = sinf(theta);
        float oc = 1.0f - c;
        const float* jp = J + ((size_t)b * NJ + i) * 3;
        int par = d_par[i];
        float tx, ty, tz;
        if (par < 0) {
            tx = jp[0]; ty = jp[1]; tz = jp[2];
        } else {
            const float* jq = J + ((size_t)b * NJ + par) * 3;
            tx = jp[0] - jq[0]; ty = jp[1] - jq[1]; tz = jp[2] - jq[2];
        }
        A_lds[i][0]  = c + oc * hx * hx;
        A_lds[i][1]  = oc * hx * hy - s * hz;
        A_lds[i][2]  = oc * hx * hz + s * hy;
        A_lds[i][3]  = tx;
        A_lds[i][4]  = oc * hy * hx + s * hz;
        A_lds[i][5]  = c + oc * hy * hy;
        A_lds[i][6]  = oc * hy * hz - s * hx;
        A_lds[i][7]  = ty;
        A_lds[i][8]  = oc * hz * hx - s * hy;
        A_lds[i][9]  = oc * hz * hy + s * hx;
        A_lds[i][10] = c + oc * hz * hz;
        A_lds[i][11] = tz;
    }
    __syncthreads();

    if (tid < NJ) {
        const int i = tid;
        float M[12];
        #pragma unroll
        for (int j = 0; j < 12; j++) M[j] = A_lds[i][j];

        for (int k = 0; k < 8; k++) {
            int p = d_anc[i][k];
            if (p < 0) break;
            float P[12];
            #pragma unroll
            for (int j = 0; j < 12; j++) P[j] = A_lds[p][j];
            float N[12];
            #pragma unroll
            for (int r = 0; r < 3; r++) {
                float p0 = P[r*4+0], p1 = P[r*4+1], p2 = P[r*4+2], p3 = P[r*4+3];
                N[r*4+0] = p0 * M[0] + p1 * M[4] + p2 * M[8];
                N[r*4+1] = p0 * M[1] + p1 * M[5] + p2 * M[9];
                N[r*4+2] = p0 * M[2] + p1 * M[6] + p2 * M[10];
                N[r*4+3] = p0 * M[3] + p1 * M[7] + p2 * M[11] + p3;
            }
            #pragma unroll
            for (int j = 0; j < 12; j++) M[j] = N[j];
        }

        const float* jp = J + ((size_t)b * NJ + i) * 3;
        float jx = jp[0], jy = jp[1], jz = jp[2];
        #pragma unroll
        for (int r = 0; r < 3; r++) {
            float g0 = M[r*4+0], g1 = M[r*4+1], g2 = M[r*4+2], g3 = M[r*4+3];
            float corr = g0 * jx + g1 * jy + g2 * jz;
            Gc_lds[i*12 + r*4+0] = g0;
            Gc_lds[i*12 + r*4+1] = g1;
            Gc_lds[i*12 + r*4+2] = g2;
            Gc_lds[i*12 + r*4+3] = g3 - corr;
        }
    }
    __syncthreads();

    // ---- Phase 1: MFMA skinning ----
    if (!wactive) return;

    float* mytl = &tl[wave * 64 * TLSTRIDE];

    // B fragment: B[k][n] = Gc[joint k][elem n], k = 8g + j; zero-padded.
    bf16x8 bfrag;
    #pragma unroll
    for (int j = 0; j < 8; j++) {
        const int k = 8 * g + j;
        const float gval = (k < NJ && n16 < 12) ? Gc_lds[k * 12 + n16] : 0.0f;
        bfrag[j] = f2bf(gval);
    }

    auto cvt = [&](float4 l4, float4 h4) {
        bf16x8 a;
        a[0] = f2bf(l4.x); a[1] = f2bf(l4.y); a[2] = f2bf(l4.z); a[3] = f2bf(l4.w);
        a[4] = f2bf(h4.x); a[5] = f2bf(h4.y); a[6] = f2bf(h4.z); a[7] = f2bf(h4.w);
        return a;
    };

    auto mfma_store = [&](int t, bf16x8 af) {
        f32x4 acc = {0.f, 0.f, 0.f, 0.f};
        acc = __builtin_amdgcn_mfma_f32_16x16x32_bf16(af, bfrag, acc, 0, 0, 0);
        #pragma unroll
        for (int r = 0; r < 4; r++) {
            const int lv = t * 16 + 4 * g + r;
            mytl[lv * TLSTRIDE + n16] = acc[r];
        }
    };

    auto epilogue = [&](int gbase, float vx, float vy, float vz) {
        __builtin_amdgcn_wave_barrier();
        const int gv = gbase + lane;
        const float* row = &mytl[lane * TLSTRIDE];
        f32x4 t0 = *(const f32x4*)(row + 0);
        f32x4 t1 = *(const f32x4*)(row + 4);
        f32x4 t2 = *(const f32x4*)(row + 8);
        if (gv < NV) {
            float* op = out + ((size_t)b * NV + gv) * 3;
            op[0] = t0[0] * vx + t0[1] * vy + t0[2] * vz + t0[3];
            op[1] = t1[0] * vx + t1[1] * vy + t1[2] * vz + t1[3];
            op[2] = t2[0] * vx + t2[1] * vy + t2[2] * vz + t2[3];
        }
        __builtin_amdgcn_wave_barrier();
    };

    // Group 0: convert prefetched W (frees pf registers) ...
    bf16x8 af0 = cvt(pfl[0], pfh[0]);
    bf16x8 af1 = cvt(pfl[1], pfh[1]);
    bf16x8 af2 = cvt(pfl[2], pfh[2]);
    bf16x8 af3 = cvt(pfl[3], pfh[3]);

    // ... immediately issue group-1's W loads (in flight under group-0's
    // MFMA + epilogue; g==3 lanes keep their zero-init values).
    #pragma unroll
    for (int t = 0; t < 4; t++) {
        if (g < 3) {
            const int v  = vwave + 64 + t * 16 + n16;
            const int vc = v < NV ? v : NV - 1;
            const float4* wp = (const float4*)(W + ((size_t)b * NV + vc) * 24 + g * 8);
            pfl[t] = wp[0];
            pfh[t] = wp[1];
        }
    }

    mfma_store(0, af0);
    mfma_store(1, af1);
    mfma_store(2, af2);
    mfma_store(3, af3);
    epilogue(vwave, v0x, v0y, v0z);

    // Group 1: consume the in-flight loads.
    af0 = cvt(pfl[0], pfh[0]);
    af1 = cvt(pfl[1], pfh[1]);
    af2 = cvt(pfl[2], pfh[2]);
    af3 = cvt(pfl[3], pfh[3]);
    mfma_store(0, af0);
    mfma_store(1, af1);
    mfma_store(2, af2);
    mfma_store(3, af3);
    epilogue(vwave + 64, v1x, v1y, v1z);
}

extern "C" void kernel_launch(void* const* d_in, const int* in_sizes, int n_in,
                              void* d_out, int out_size, void* d_ws, size_t ws_size,
                              hipStream_t stream) {
    const float* V    = (const float*)d_in[0];
    const float* J    = (const float*)d_in[1];
    const float* pose = (const float*)d_in[2];
    const float* W    = (const float*)d_in[3];
    float* out = (float*)d_out;

    dim3 grid((NV + 511) / 512, NB);
    lbs_fused<<<grid, 256, 0, stream>>>(V, J, pose, W, out);
}